// Round 10
// baseline (599.964 us; speedup 1.0000x reference)
//
#include <hip/hip_runtime.h>
#include <hip/hip_fp16.h>
#include <math.h>

#define D 32
#define ROWU 16           // uints per bf16 row (32 bf16 = 64 B)
#define NBK 1024          // bucket slots per segment
#define BSHIFT 8          // bucket = node >> 8  (256 nodes per bucket)
#define TILE_H 16384      // undirected edges per hist block
#define TILE_BIN 2048     // undirected edges per bin block (8 per thread)
#define SQB 104           // sumsq blocks

typedef unsigned int u32;
typedef unsigned short u16;

__device__ __forceinline__ float logsigf(float x) {
  return fminf(x, 0.f) - log1pf(expf(-fabsf(x)));
}

// ---- bf16 helpers (storage bf16, math fp32) ----
__device__ __forceinline__ float lo16(u32 u) { return __uint_as_float(u << 16); }
__device__ __forceinline__ float hi16(u32 u) { return __uint_as_float(u & 0xFFFF0000u); }
__device__ __forceinline__ u32 pk2(float a, float b) {  // RNE pack
  u32 ua = __float_as_uint(a), ub = __float_as_uint(b);
  u32 ra = (ua + 0x7FFFu + ((ua >> 16) & 1u)) >> 16;
  u32 rb = (ub + 0x7FFFu + ((ub >> 16) & 1u)) >> 16;
  return (ra & 0xFFFFu) | (rb << 16);
}
__device__ __forceinline__ float bfat(const u16* __restrict__ p, size_t off) {
  return __uint_as_float(((u32)p[off]) << 16);
}
__device__ __forceinline__ void accum8(float* a, float w, uint4 x) {
  a[0] += w * lo16(x.x); a[1] += w * hi16(x.x);
  a[2] += w * lo16(x.y); a[3] += w * hi16(x.y);
  a[4] += w * lo16(x.z); a[5] += w * hi16(x.z);
  a[6] += w * lo16(x.w); a[7] += w * hi16(x.w);
}
__device__ __forceinline__ uint4 pack8(const float* a, float w) {
  return make_uint4(pk2(w * a[0], w * a[1]), pk2(w * a[2], w * a[3]),
                    pk2(w * a[4], w * a[5]), pk2(w * a[6], w * a[7]));
}

// ---- fp16 weight-pair pack/unpack ----
__device__ __forceinline__ u32 wpack(float a, float b) {
  __half2 h = __floats2half2_rn(a, b);
  return *reinterpret_cast<u32*>(&h);
}
__device__ __forceinline__ float2 hun(int wb) {
  __half2 h;
  *reinterpret_cast<int*>(&h) = wb;
  return __half22float2(h);
}

// ================= CSR build via bucket binning =================
// seg 0 = tgt, 1 = aux0, 2 = aux1. Directed entry packed: (dst_local<<18)|src.

// Fused: hist blocks (x < histB) + emb bf16 conversion blocks (independent).
__global__ void hist_cvt_kernel(const int2* __restrict__ tgt, const int2* __restrict__ aux,
                                int E, int Nu, int BPS, int histB, int* __restrict__ bcur,
                                const float4* __restrict__ ue, long nu2h,
                                const float4* __restrict__ ie, long ni2h,
                                u32* __restrict__ emb) {
  __shared__ int lh[NBK];
  int x = blockIdx.x;
  if (x >= histB) {
    long i2 = (long)(x - histB) * blockDim.x + threadIdx.x;
    if (i2 < nu2h + ni2h) {
      float4 v = (i2 < nu2h) ? ue[i2] : ie[i2 - nu2h];
      uint2 o = make_uint2(pk2(v.x, v.y), pk2(v.z, v.w));
      *reinterpret_cast<uint2*>(emb + 2 * i2) = o;
    }
    return;
  }
  int seg = x / BPS;
  int blk = x - seg * BPS;
  const int2* edges = (seg == 0) ? tgt : aux + (size_t)(seg - 1) * E;
  for (int b = threadIdx.x; b < NBK; b += 256) lh[b] = 0;
  __syncthreads();
  int e0 = blk * TILE_H;
  for (int k = threadIdx.x; k < TILE_H; k += 256) {
    int e = e0 + k;
    if (e < E) {
      int2 ed = edges[e];
      atomicAdd(&lh[ed.x >> BSHIFT], 1);
      atomicAdd(&lh[(ed.y + Nu) >> BSHIFT], 1);
    }
  }
  __syncthreads();
  for (int b = threadIdx.x; b < NBK; b += 256)
    if (lh[b]) atomicAdd(&bcur[seg * NBK + b], lh[b]);
}

__global__ void bscan_kernel(int* __restrict__ bcur) {
  int* b = bcur + blockIdx.x * NBK;
  int lane = threadIdx.x;
  int carry = 0;
  for (int base = 0; base < NBK; base += 64) {
    int i = base + lane;
    int v = b[i];
    int s = v;
    #pragma unroll
    for (int o = 1; o < 64; o <<= 1) {
      int t = __shfl_up(s, o);
      if (lane >= o) s += t;
    }
    b[i] = carry + s - v;
    carry += __shfl(s, 63);
  }
}

// Two-pass binning, zero per-thread staging (no scratch spills):
// pass A counts into LDS; reserve global ranges + reset counters; pass B
// re-reads the L2-hot edge tile, recomputes bucket+rank, writes directly.
__global__ void bin_kernel(const int2* __restrict__ tgt, const int2* __restrict__ aux,
                           int E, int Nu, int BPS, int* __restrict__ bcur,
                           int* __restrict__ binned) {
  __shared__ int lh[NBK];
  __shared__ int gb[NBK];
  int seg = blockIdx.x / BPS;
  int blk = blockIdx.x - seg * BPS;
  const int2* edges = (seg == 0) ? tgt : aux + (size_t)(seg - 1) * E;
  int* out = binned + (size_t)seg * 2 * E;
  int tid = threadIdx.x;
  for (int b = tid; b < NBK; b += 256) lh[b] = 0;
  __syncthreads();
  int e0 = blk * TILE_BIN;
  // pass A: bucket counts only
  #pragma unroll
  for (int it = 0; it < 8; ++it) {
    int e = e0 + tid + it * 256;
    if (e < E) {
      int2 ed = edges[e];
      atomicAdd(&lh[ed.x >> BSHIFT], 1);
      atomicAdd(&lh[(ed.y + Nu) >> BSHIFT], 1);
    }
  }
  __syncthreads();
  // reserve contiguous global ranges; reset counters for rank pass
  #pragma unroll
  for (int j = 0; j < 4; ++j) {
    int b = tid * 4 + j;
    int c = lh[b];
    gb[b] = c ? atomicAdd(&bcur[seg * NBK + b], c) : 0;
    lh[b] = 0;
  }
  __syncthreads();
  // pass B: re-read tile (L2-hot), rank + direct write
  #pragma unroll
  for (int it = 0; it < 8; ++it) {
    int e = e0 + tid + it * 256;
    if (e < E) {
      int2 ed = edges[e];
      int u = ed.x, v = ed.y + Nu;
      int b1 = u >> BSHIFT, b2 = v >> BSHIFT;
      int r1 = atomicAdd(&lh[b1], 1);
      out[gb[b1] + r1] = ((u & 255) << 18) | v;
      int r2 = atomicAdd(&lh[b2], 1);
      out[gb[b2] + r2] = ((v & 255) << 18) | u;
    }
  }
}

// Count pass: per-node degree + row pointers (absolute within segment).
__global__ void csr_count_kernel(const int* __restrict__ binned,
                                 const int* __restrict__ bend, int E2, int N, int NBKe,
                                 int* __restrict__ deg3, int* __restrict__ rp3) {
  __shared__ int cnt[256];
  __shared__ int wred[4];
  int seg = blockIdx.x / NBKe;
  int bkt = blockIdx.x - seg * NBKe;
  int node0 = bkt << BSHIFT;
  const int* bc = bend + seg * NBK;
  int start = (bkt == 0) ? 0 : bc[bkt - 1];
  int end = bc[bkt];
  int cntE = end - start;
  const int* src = binned + (size_t)seg * E2 + start;
  cnt[threadIdx.x] = 0;
  __syncthreads();
  for (int k = threadIdx.x; k < cntE; k += 256) atomicAdd(&cnt[src[k] >> 18], 1);
  __syncthreads();
  int lane = threadIdx.x & 63, wid = threadIdx.x >> 6;
  int v = cnt[threadIdx.x];
  int incl = v;
  #pragma unroll
  for (int o = 1; o < 64; o <<= 1) {
    int t = __shfl_up(incl, o);
    if (lane >= o) incl += t;
  }
  if (lane == 63) wred[wid] = incl;
  __syncthreads();
  int wbase = 0;
  for (int w = 0; w < wid; ++w) wbase += wred[w];
  int node = node0 + (int)threadIdx.x;
  if (node < N) {
    deg3[(size_t)seg * N + node] = v;
    rp3[(size_t)seg * (N + 1) + node] = start + wbase + incl - v;
  }
  if (bkt == 0 && threadIdx.x == 0) rp3[(size_t)seg * (N + 1) + N] = E2;
}

// dinv + packed per-segment half2 weight tables (L2-resident, used by scatter).
__global__ void dinv_all_kernel(const int* __restrict__ deg3, float* __restrict__ dinv5,
                                u32* __restrict__ wtab, int N) {
  int n = blockIdx.x * blockDim.x + threadIdx.x;
  if (n >= N) return;
  int dt = deg3[n], d0 = deg3[N + n], d1 = deg3[2 * N + n];
  float wt  = dt ? rsqrtf((float)dt) : 0.f;
  float wa0 = d0 ? rsqrtf((float)d0) : 0.f;
  float wa1 = d1 ? rsqrtf((float)d1) : 0.f;
  int c0 = dt + d0, c1 = dt + d1;
  float wc0 = c0 ? rsqrtf((float)c0) : 0.f;
  float wc1 = c1 ? rsqrtf((float)c1) : 0.f;
  dinv5[n] = wt;
  dinv5[N + n] = wa0;
  dinv5[2 * N + n] = wa1;
  dinv5[3 * N + n] = wc0;
  dinv5[4 * N + n] = wc1;
  wtab[n] = wpack(wc0, wc1);
  wtab[N + n] = wpack(wa0, wc0);
  wtab[2 * N + n] = wpack(wa1, wc1);
}

// Scatter pass (after dinv): write packed 8B entries {col, half2 weights from wtab}.
__global__ void csr_scatter_kernel(const int* __restrict__ binned,
                                   const int* __restrict__ bend,
                                   const int* __restrict__ rp3,
                                   const u32* __restrict__ wtab,
                                   int E2, int N, int NBKe,
                                   int2* __restrict__ pk) {
  __shared__ int cnt[256];
  __shared__ int off[256];
  int seg = blockIdx.x / NBKe;
  int bkt = blockIdx.x - seg * NBKe;
  int node0 = bkt << BSHIFT;
  const int* bc = bend + seg * NBK;
  int start = (bkt == 0) ? 0 : bc[bkt - 1];
  int end = bc[bkt];
  int cntE = end - start;
  const int* src = binned + (size_t)seg * E2 + start;
  int node = node0 + (int)threadIdx.x;
  off[threadIdx.x] = (node < N) ? rp3[(size_t)seg * (N + 1) + node] : 0;
  cnt[threadIdx.x] = 0;
  const u32* wt = wtab + (size_t)seg * N;
  __syncthreads();
  int2* out = pk + (size_t)seg * E2;
  for (int k = threadIdx.x; k < cntE; k += 256) {
    int en = src[k];
    int lb = en >> 18;
    int c = en & 0x3FFFF;
    int pos = atomicAdd(&cnt[lb], 1);
    out[off[lb] + pos] = make_int2(c, (int)wt[c]);
  }
}

// ================= dense propagation (bf16 rows) =================

__device__ __forceinline__ void edge1_dual(const int2* __restrict__ p, int j, int lane,
                                           const uint4* __restrict__ rows,
                                           float* a1, float* a2) {
  int2 en = p[j];
  float2 w = hun(en.y);
  uint4 x = rows[(size_t)en.x * 4 + lane];
  accum8(a1, w.x, x);
  accum8(a2, w.y, x);
}

__device__ __forceinline__ void stream_dual(const int* __restrict__ rp,
                                            const int2* __restrict__ p, int n, int lane,
                                            const uint4* __restrict__ rows,
                                            float* a1, float* a2) {
  int j = rp[n], e = rp[n + 1];
  if ((j & 1) && j < e) { edge1_dual(p, j, lane, rows, a1, a2); ++j; }
  for (; j + 3 < e; j += 4) {
    int4 m0 = *reinterpret_cast<const int4*>(p + j);
    int4 m1 = *reinterpret_cast<const int4*>(p + j + 2);
    uint4 x0 = rows[(size_t)m0.x * 4 + lane];
    uint4 x1 = rows[(size_t)m0.z * 4 + lane];
    uint4 x2 = rows[(size_t)m1.x * 4 + lane];
    uint4 x3 = rows[(size_t)m1.z * 4 + lane];
    float2 w0 = hun(m0.y), w1 = hun(m0.w), w2 = hun(m1.y), w3 = hun(m1.w);
    accum8(a1, w0.x, x0); accum8(a2, w0.y, x0);
    accum8(a1, w1.x, x1); accum8(a2, w1.y, x1);
    accum8(a1, w2.x, x2); accum8(a2, w2.y, x2);
    accum8(a1, w3.x, x3); accum8(a2, w3.y, x3);
  }
  for (; j < e; ++j) edge1_dual(p, j, lane, rows, a1, a2);
}

// layer-1 for BOTH idx. tgt rows read ONCE. 4 lanes/node.
__global__ void gather_fused_all_kernel(const int* __restrict__ rp3,
                                        const int2* __restrict__ pk,
                                        const float* __restrict__ dinv5,
                                        const uint4* __restrict__ emb,
                                        uint4* __restrict__ BaAll, uint4* __restrict__ BcAll,
                                        int N, int E2) {
  const int* rpA0 = rp3 + (size_t)(N + 1);
  const int* rpA1 = rp3 + 2 * (size_t)(N + 1);
  const int2* pT = pk;
  const int2* pA0 = pk + (size_t)E2;
  const int2* pA1 = pk + 2 * (size_t)E2;
  const float* dvA0 = dinv5 + (size_t)N;
  const float* dvA1 = dinv5 + 2 * (size_t)N;
  const float* dvC0 = dinv5 + 3 * (size_t)N;
  const float* dvC1 = dinv5 + 4 * (size_t)N;
  int t = blockIdx.x * blockDim.x + threadIdx.x;
  int n = t >> 2;
  if (n >= N) return;
  int lane = t & 3;
  float aA0[8] = {0, 0, 0, 0, 0, 0, 0, 0};
  float aA1[8] = {0, 0, 0, 0, 0, 0, 0, 0};
  float aC0[8] = {0, 0, 0, 0, 0, 0, 0, 0};
  float aC1[8] = {0, 0, 0, 0, 0, 0, 0, 0};
  stream_dual(rpA0, pA0, n, lane, emb, aA0, aC0);   // seg1: (wA0, wC0)
  stream_dual(rpA1, pA1, n, lane, emb, aA1, aC1);   // seg2: (wA1, wC1)
  stream_dual(rp3, pT, n, lane, emb, aC0, aC1);     // seg0: (wC0, wC1)
  size_t o = (size_t)n * 4 + lane;
  size_t rowN4 = (size_t)N * 4;
  BaAll[o] = pack8(aA0, dvA0[n]);
  BaAll[rowN4 + o] = pack8(aA1, dvA1[n]);
  BcAll[o] = pack8(aC0, dvC0[n]);
  BcAll[rowN4 + o] = pack8(aC1, dvC1[n]);
}

// ---- fused gather_avg + ce_sparse bodies (independent; co-scheduled) ----

__device__ __forceinline__ void gather_avg_body(int bx, int idx,
                                  const int* __restrict__ rp3, const int2* __restrict__ pk,
                                  const float* __restrict__ dinv5,
                                  const uint4* __restrict__ emb,
                                  const uint4* __restrict__ BaAll, uint4* __restrict__ AI,
                                  int N, int E2) {
  const int* rp = rp3 + (size_t)(1 + idx) * (N + 1);
  const int2* pA = pk + (size_t)(1 + idx) * E2;
  const float* dv = dinv5 + (size_t)(1 + idx) * N;
  const uint4* cur = BaAll + (size_t)idx * N * 4;
  int t = bx * 256 + threadIdx.x;
  int n = t >> 2;
  if (n >= N) return;
  int lane = t & 3;
  float acc[8] = {0, 0, 0, 0, 0, 0, 0, 0};
  int j = rp[n], e = rp[n + 1];
  if ((j & 1) && j < e) {
    int2 en = pA[j];
    uint4 x = cur[(size_t)en.x * 4 + lane];
    accum8(acc, hun(en.y).x, x);
    ++j;
  }
  for (; j + 3 < e; j += 4) {
    int4 m0 = *reinterpret_cast<const int4*>(pA + j);
    int4 m1 = *reinterpret_cast<const int4*>(pA + j + 2);
    uint4 x0 = cur[(size_t)m0.x * 4 + lane];
    uint4 x1 = cur[(size_t)m0.z * 4 + lane];
    uint4 x2 = cur[(size_t)m1.x * 4 + lane];
    uint4 x3 = cur[(size_t)m1.z * 4 + lane];
    accum8(acc, hun(m0.y).x, x0);
    accum8(acc, hun(m0.w).x, x1);
    accum8(acc, hun(m1.y).x, x2);
    accum8(acc, hun(m1.w).x, x3);
  }
  for (; j < e; ++j) {
    int2 en = pA[j];
    uint4 x = cur[(size_t)en.x * 4 + lane];
    accum8(acc, hun(en.y).x, x);
  }
  float wn = dv[n];
  uint4 e4 = emb[(size_t)n * 4 + lane];
  uint4 b4 = cur[(size_t)n * 4 + lane];
  float r[8];
  r[0] = (lo16(e4.x) + lo16(b4.x) + wn * acc[0]) * (1.f / 3.f);
  r[1] = (hi16(e4.x) + hi16(b4.x) + wn * acc[1]) * (1.f / 3.f);
  r[2] = (lo16(e4.y) + lo16(b4.y) + wn * acc[2]) * (1.f / 3.f);
  r[3] = (hi16(e4.y) + hi16(b4.y) + wn * acc[3]) * (1.f / 3.f);
  r[4] = (lo16(e4.z) + lo16(b4.z) + wn * acc[4]) * (1.f / 3.f);
  r[5] = (hi16(e4.z) + hi16(b4.z) + wn * acc[5]) * (1.f / 3.f);
  r[6] = (lo16(e4.w) + lo16(b4.w) + wn * acc[6]) * (1.f / 3.f);
  r[7] = (hi16(e4.w) + hi16(b4.w) + wn * acc[7]) * (1.f / 3.f);
  AI[(size_t)n * 8 + idx * 4 + lane] = pack8(r, 1.f);
}

__device__ __forceinline__ float fdim2(const int2* __restrict__ pkA, const int2* __restrict__ pkT,
                                       const int* __restrict__ rpA, const int* __restrict__ rpT,
                                       int idx, const float* __restrict__ dv,
                                       const u16* __restrict__ base, const u16* __restrict__ L1,
                                       int r, int d) {
  float acc = 0.f;
  for (int j = rpA[r]; j < rpA[r + 1]; ++j) {
    int2 en = pkA[j];
    acc += hun(en.y).y * bfat(L1, (size_t)en.x * D + d);
  }
  for (int j = rpT[r]; j < rpT[r + 1]; ++j) {
    int2 en = pkT[j];
    float2 w = hun(en.y);
    acc += (idx ? w.y : w.x) * bfat(L1, (size_t)en.x * D + d);
  }
  return (bfat(base, (size_t)r * D + d) + bfat(L1, (size_t)r * D + d) + dv[r] * acc) * (1.f / 3.f);
}

__device__ __forceinline__ void ce_body(int bx, int idx,
                                 const int* __restrict__ rp3, const int2* __restrict__ pk,
                                 const float* __restrict__ dinv5,
                                 const u32* __restrict__ EMBu, const u32* __restrict__ BcAll,
                                 const int* __restrict__ batch, int Bsz, int Nu, int N, int E2,
                                 float* __restrict__ cps, float* __restrict__ cns) {
  const int* rpA = rp3 + (size_t)(1 + idx) * (N + 1);
  const int2* pkA = pk + (size_t)(1 + idx) * E2;
  const float* dv = dinv5 + (size_t)(3 + idx) * N;
  const u16* base = (const u16*)EMBu;
  const u16* L1 = (const u16*)(BcAll + (size_t)idx * N * ROWU);
  float* outp = cps + (size_t)idx * Bsz;
  float* outn = cns + (size_t)idx * Bsz;
  int t = bx * 256 + threadIdx.x;
  int b = t >> 5, d = t & 31;
  if (b >= Bsz) return;
  int u = batch[b * 9 + 0];
  int p = batch[b * 9 + 1] + Nu;
  int n = batch[b * 9 + 2] + Nu;
  float uv = fdim2(pkA, pk, rpA, rp3, idx, dv, base, L1, u, d);
  float pv = fdim2(pkA, pk, rpA, rp3, idx, dv, base, L1, p, d);
  float nv = fdim2(pkA, pk, rpA, rp3, idx, dv, base, L1, n, d);
  float sp = uv * pv, sn = uv * nv;
  #pragma unroll
  for (int o = 16; o > 0; o >>= 1) {
    sp += __shfl_down(sp, o, 32);
    sn += __shfl_down(sn, o, 32);
  }
  if (d == 0) {
    outp[b] = fmaxf(sp, 0.f);
    outn[b] = fmaxf(sn, 0.f);
  }
}

// LPT co-schedule: ce blocks (heavy, ~8x per-thread work) are issued within
// the FIRST 2*CEB blocks (mod-2 interleave) so they start at t=0 and the
// lighter avg sea fills in behind them -- removes the late pure-ce tail.
__global__ void gather_avg_ce_kernel(const int* __restrict__ rp3, const int2* __restrict__ pk,
                                     const float* __restrict__ dinv5,
                                     const uint4* __restrict__ emb,
                                     const uint4* __restrict__ BaAll, uint4* __restrict__ AI,
                                     const u32* __restrict__ EMBu, const u32* __restrict__ BcAll,
                                     const int* __restrict__ batch, int Bsz, int Nu,
                                     int N, int E2, int CEB,
                                     float* __restrict__ cps, float* __restrict__ cns) {
  int x = blockIdx.x;
  int idx = blockIdx.y;
  int lim = 2 * CEB;
  if (x < lim && (x & 1)) {
    ce_body(x >> 1, idx, rp3, pk, dinv5, EMBu, BcAll, batch, Bsz, Nu, N, E2, cps, cns);
  } else {
    int ceBefore = (x < lim) ? ((x + 1) >> 1) : CEB;
    gather_avg_body(x - ceBefore, idx, rp3, pk, dinv5, emb, BaAll, AI, N, E2);
  }
}

// ---- fused de_gather + score_aux + sumsq2 (independent; score/sumsq first) ----

__device__ __forceinline__ float dotrow(const u32* __restrict__ a, const u32* __restrict__ b) {
  float s = 0.f;
  #pragma unroll
  for (int k = 0; k < ROWU; ++k) {
    u32 x = a[k], y = b[k];
    s += lo16(x) * lo16(y) + hi16(x) * hi16(y);
  }
  return s;
}

__global__ void de_score_sumsq_kernel(const int* __restrict__ rp3, const int2* __restrict__ pk,
                                      const float* __restrict__ dinv5,
                                      const uint4* __restrict__ AI4, uint4* __restrict__ DeI,
                                      const u32* __restrict__ AI, const int* __restrict__ batch,
                                      int Bsz, int Nu, int N, int NA, int gBs,
                                      float* __restrict__ aps, float* __restrict__ ans_,
                                      float* __restrict__ accs,
                                      const float4* __restrict__ xu, int n4u,
                                      const float4* __restrict__ xi, int n4i) {
  __shared__ float redU[4], redI[4];
  int x = blockIdx.x;
  int scoreB = gBs * NA;
  int tid = threadIdx.x;
  if (x < scoreB) {
    // ---- score_aux ----
    int idx = x / gBs;
    int bx = x - idx * gBs;
    const u32* A = AI + (size_t)idx * ROWU;
    float* outp = aps + (size_t)idx * Bsz;
    float* outn = ans_ + (size_t)idx * Bsz;
    int b = bx * 256 + tid;
    float l = 0.f;
    if (b < Bsz) {
      int u = batch[b * 9 + 0];
      int p = batch[b * 9 + 1] + Nu;
      int n = batch[b * 9 + 2] + Nu;
      const u32* ur = A + (size_t)u * 32;
      outp[b] = fmaxf(dotrow(ur, A + (size_t)p * 32), 0.f);
      outn[b] = fmaxf(dotrow(ur, A + (size_t)n * 32), 0.f);
      const int* r = batch + b * 9 + 3 * (1 + idx);
      const u32* aur = A + (size_t)r[0] * 32;
      float ps = dotrow(aur, A + (size_t)(r[1] + Nu) * 32);
      float ns = dotrow(aur, A + (size_t)(r[2] + Nu) * 32);
      l = -logsigf(ps - ns);
    }
    for (int o = 32; o > 0; o >>= 1) l += __shfl_down(l, o);
    if ((tid & 63) == 0) atomicAdd(&accs[idx], l);
    return;
  }
  if (x < scoreB + SQB) {
    // ---- sumsq2 ----
    int bx = x - scoreB;
    int gid = bx * 256 + tid;
    int stride = SQB * 256;
    float su = 0.f, si = 0.f;
    for (int i = gid; i < n4u; i += stride) {
      float4 v = xu[i];
      su += v.x * v.x + v.y * v.y + v.z * v.z + v.w * v.w;
    }
    for (int i = gid; i < n4i; i += stride) {
      float4 v = xi[i];
      si += v.x * v.x + v.y * v.y + v.z * v.z + v.w * v.w;
    }
    for (int o = 32; o > 0; o >>= 1) {
      su += __shfl_down(su, o);
      si += __shfl_down(si, o);
    }
    if ((tid & 63) == 0) { redU[tid >> 6] = su; redI[tid >> 6] = si; }
    __syncthreads();
    if (tid == 0) {
      atomicAdd(&accs[NA + 1], redU[0] + redU[1] + redU[2] + redU[3]);
      atomicAdd(&accs[NA + 2], redI[0] + redI[1] + redI[2] + redI[3]);
    }
    return;
  }
  // ---- de_gather ----
  int bx = x - scoreB - SQB;
  int t = bx * 256 + tid;
  int n = t >> 3;
  if (n >= N) return;
  int lane = t & 7;
  float acc[8] = {0, 0, 0, 0, 0, 0, 0, 0};
  int j = rp3[n], e = rp3[n + 1];
  if ((j & 1) && j < e) {
    int c = pk[j].x;
    uint4 xr = AI4[(size_t)c * 8 + lane];
    accum8(acc, dinv5[c], xr);
    ++j;
  }
  for (; j + 3 < e; j += 4) {
    int4 m0 = *reinterpret_cast<const int4*>(pk + j);
    int4 m1 = *reinterpret_cast<const int4*>(pk + j + 2);
    uint4 x0 = AI4[(size_t)m0.x * 8 + lane];
    uint4 x1 = AI4[(size_t)m0.z * 8 + lane];
    uint4 x2 = AI4[(size_t)m1.x * 8 + lane];
    uint4 x3 = AI4[(size_t)m1.z * 8 + lane];
    accum8(acc, dinv5[m0.x], x0);
    accum8(acc, dinv5[m0.z], x1);
    accum8(acc, dinv5[m1.x], x2);
    accum8(acc, dinv5[m1.z], x3);
  }
  for (; j < e; ++j) {
    int c = pk[j].x;
    uint4 xr = AI4[(size_t)c * 8 + lane];
    accum8(acc, dinv5[c], xr);
  }
  DeI[(size_t)n * 8 + lane] = pack8(acc, dinv5[n]);
}

// ================= de sparse + recloss fused =================
// 64 lanes per batch item: idx = lane>>5, d = lane&31. Both idx halves share
// each 128 B interleaved AI/DeI row and the tgt edge walk; BPR rec-loss
// finished in-register via cross-half shuffles.

__device__ __forceinline__ float fdim1i(const int2* __restrict__ pkT, const int* __restrict__ rp,
                                        const float* __restrict__ dv,
                                        const u16* __restrict__ base, const u16* __restrict__ L1,
                                        int r, int di) {
  float acc = 0.f;
  for (int j = rp[r]; j < rp[r + 1]; ++j) {
    int2 en = pkT[j];
    acc += dv[en.x] * bfat(L1, (size_t)en.x * 64 + di);
  }
  return (bfat(base, (size_t)r * 64 + di) + bfat(L1, (size_t)r * 64 + di) + dv[r] * acc) * (1.f / 3.f);
}

__global__ void de_sparse_rec_kernel(const int* __restrict__ rp3, const int2* __restrict__ pk,
                                     const float* __restrict__ dinv5,
                                     const u32* __restrict__ AI, const u32* __restrict__ DeI,
                                     const int* __restrict__ batch,
                                     const float* __restrict__ cps, const float* __restrict__ cns,
                                     const float* __restrict__ aps, const float* __restrict__ ans_,
                                     int Bsz, int Nu, int N, int NA, float* __restrict__ acc) {
  __shared__ float red[4];
  int tid = threadIdx.x;
  int t = blockIdx.x * 256 + tid;
  int b = t >> 6;
  int lane = tid & 63;
  int d = lane & 31;
  int idx = lane >> 5;
  float l = 0.f;
  if (b < Bsz) {
    const u16* base = (const u16*)AI;
    const u16* L1 = (const u16*)DeI;
    int di = idx * 32 + d;
    int u = batch[b * 9 + 0];
    int p = batch[b * 9 + 1] + Nu;
    int n = batch[b * 9 + 2] + Nu;
    float uv = fdim1i(pk, rp3, dinv5, base, L1, u, di);
    float pv = fdim1i(pk, rp3, dinv5, base, L1, p, di);
    float nv = fdim1i(pk, rp3, dinv5, base, L1, n, di);
    float sp = uv * pv, sn = uv * nv;
    #pragma unroll
    for (int o = 16; o > 0; o >>= 1) {
      sp += __shfl_xor(sp, o, 32);
      sn += __shfl_xor(sn, o, 32);
    }
    sp = fmaxf(sp, 0.f);           // per-idx relu'd de score, in all 32 lanes of half
    sn = fmaxf(sn, 0.f);
    float dp = sp + __shfl_xor(sp, 32);   // sum over idx (width 64)
    float dn = sn + __shfl_xor(sn, 32);
    if (lane == 0) {
      float cap = 0.f, can = 0.f;
      for (int i = 0; i < NA; ++i) {
        cap += cps[(size_t)i * Bsz + b] * aps[(size_t)i * Bsz + b];
        can += cns[(size_t)i * Bsz + b] * ans_[(size_t)i * Bsz + b];
      }
      l = -logsigf(dp * cap - dn * can);
    }
  }
  if ((tid & 63) == 0) red[tid >> 6] = l;
  __syncthreads();
  if (tid == 0) atomicAdd(acc, red[0] + red[1] + red[2] + red[3]);
}

__global__ void final_kernel(const float* __restrict__ accs, int Bsz, int NA, int NiRows,
                             float* __restrict__ out) {
  float rec = accs[NA] / (float)Bsz;
  float aux = 0.f;
  for (int i = 0; i < NA; ++i) aux += accs[i] / (float)Bsz;
  aux /= (float)NA;
  float embl = (sqrtf(accs[NA + 1]) + sqrtf(accs[NA + 2])) / (float)NiRows;
  out[0] = rec + 0.5f * aux + 1e-4f * embl;
}

extern "C" void kernel_launch(void* const* d_in, const int* in_sizes, int n_in,
                              void* d_out, int out_size, void* d_ws, size_t ws_size,
                              hipStream_t stream) {
  const float* user_emb = (const float*)d_in[0];
  const float* item_emb = (const float*)d_in[1];
  const int* batch = (const int*)d_in[2];
  const int* aux_edges = (const int*)d_in[3];
  const int* tgt_edges = (const int*)d_in[4];

  const int NuRows = in_sizes[0] / D;          // 100001
  const int NiRows = in_sizes[1] / D;          // 50001
  const int Bsz = in_sizes[2] / 9;             // 4096
  const int E = in_sizes[4] / 2;               // 1,000,000
  const int NA = in_sizes[3] / (2 * E);        // 2
  const int N = NuRows + NiRows;               // 150002 < 2^18 (pack invariant)
  const int E2 = 2 * E;
  const size_t rowH = (size_t)N * ROWU;
  const int BPS_H = (E + TILE_H - 1) / TILE_H;
  const int BPS_B = (E + TILE_BIN - 1) / TILE_BIN;
  const int NBKe = (N + (1 << BSHIFT) - 1) >> BSHIFT;

  // ---- workspace layout ----
  u32* EMBu = (u32*)d_ws;                 // rowH (planar)
  u32* AI = EMBu + rowH;                  // 2*rowH (INTERLEAVED per node)
  u32* BaAll = AI + 2 * rowH;             // 2*rowH (planar aux L1; later interleaved De)
  u32* BcAll = BaAll + 2 * rowH;          // 2*rowH (planar comb L1)
  int* deg3 = (int*)(BcAll + 2 * rowH);           // 3*N
  float* dinv5 = (float*)(deg3 + 3 * (size_t)N);  // 5*N
  u32* wtab = (u32*)(dinv5 + 5 * (size_t)N);      // 3*N packed half2 weight tables
  int* rp3 = (int*)(wtab + 3 * (size_t)N);        // 3*(N+1)
  int* bcur = rp3 + 3 * (size_t)(N + 1);          // 3*NBK
  uintptr_t pka = ((uintptr_t)(bcur + 3 * (size_t)NBK) + 15) & ~(uintptr_t)15;
  int2* pk = (int2*)pka;                          // 3*E2 packed entries (8 B each), 16B-aligned
  float* cps = (float*)(pk + 3 * (size_t)E2);
  float* cns = cps + (size_t)NA * Bsz;
  float* aps = cns + (size_t)NA * Bsz;
  float* ans_ = aps + (size_t)NA * Bsz;
  float* accs = ans_ + (size_t)NA * Bsz;          // [NA aux][rec][sumsq_u][sumsq_i]
  int* binned = (int*)AI;  // 24 MB alias spanning AI+BaAll; dead before gathers

  const int TB = 256;
  const int gN = (N + TB - 1) / TB;
  const int gN4 = (N * 4 + TB - 1) / TB;
  const int gN8 = (N * 8 + TB - 1) / TB;
  const int gB = (Bsz + TB - 1) / TB;
  const int gB32 = (Bsz * 32 + TB - 1) / TB;
  const int gB64 = (Bsz * 64 + TB - 1) / TB;
  const long nu2 = (long)NuRows * ROWU;
  const long ni2 = (long)NiRows * ROWU;
  const long nu2h = nu2 / 2, ni2h = ni2 / 2;
  const int gCvt2 = (int)((nu2h + ni2h + TB - 1) / TB);
  const int histB = 3 * BPS_H;

  // ---- binned CSR build (+ emb conversion co-scheduled) ----
  hipMemsetAsync(bcur, 0, 3 * (size_t)NBK * sizeof(int), stream);
  hist_cvt_kernel<<<histB + gCvt2, TB, 0, stream>>>(
      (const int2*)tgt_edges, (const int2*)aux_edges, E, NuRows, BPS_H, histB, bcur,
      (const float4*)user_emb, nu2h, (const float4*)item_emb, ni2h, EMBu);
  bscan_kernel<<<3, 64, 0, stream>>>(bcur);
  bin_kernel<<<3 * BPS_B, TB, 0, stream>>>((const int2*)tgt_edges, (const int2*)aux_edges,
                                           E, NuRows, BPS_B, bcur, binned);
  csr_count_kernel<<<3 * NBKe, TB, 0, stream>>>(binned, bcur, E2, N, NBKe, deg3, rp3);
  dinv_all_kernel<<<gN, TB, 0, stream>>>(deg3, dinv5, wtab, N);
  csr_scatter_kernel<<<3 * NBKe, TB, 0, stream>>>(binned, bcur, rp3, wtab, E2, N, NBKe, pk);

  hipMemsetAsync(accs, 0, (size_t)(NA + 3) * sizeof(float), stream);

  gather_fused_all_kernel<<<gN4, TB, 0, stream>>>(rp3, pk, dinv5, (const uint4*)EMBu,
                                                  (uint4*)BaAll, (uint4*)BcAll, N, E2);

  dim3 gridAC(gN4 + gB32, NA);
  gather_avg_ce_kernel<<<gridAC, TB, 0, stream>>>(rp3, pk, dinv5, (const uint4*)EMBu,
                                                  (const uint4*)BaAll, (uint4*)AI,
                                                  EMBu, BcAll, batch, Bsz, NuRows,
                                                  N, E2, gB32, cps, cns);

  de_score_sumsq_kernel<<<gB * NA + SQB + gN8, TB, 0, stream>>>(
      rp3, pk, dinv5, (const uint4*)AI, (uint4*)BaAll, AI, batch,
      Bsz, NuRows, N, NA, gB, aps, ans_, accs,
      (const float4*)user_emb, (int)((size_t)NuRows * D / 4),
      (const float4*)item_emb, (int)((size_t)NiRows * D / 4));

  de_sparse_rec_kernel<<<gB64, TB, 0, stream>>>(rp3, pk, dinv5, AI, (const u32*)BaAll,
                                                batch, cps, cns, aps, ans_,
                                                Bsz, NuRows, N, NA, accs + NA);

  final_kernel<<<1, 1, 0, stream>>>(accs, Bsz, NA, NiRows, (float*)d_out);
}

// Round 11
// 561.091 us; speedup vs baseline: 1.0693x; 1.0693x over previous
//
#include <hip/hip_runtime.h>
#include <hip/hip_fp16.h>
#include <math.h>

#define D 32
#define ROWU 16           // uints per bf16 row (32 bf16 = 64 B)
#define NBK 1024          // bucket slots per segment
#define BSHIFT 8          // bucket = node >> 8  (256 nodes per bucket)
#define TILE_H 16384      // undirected edges per hist block
#define TILE_BIN 2048     // undirected edges per bin block (8 per thread)
#define SQB 104           // sumsq blocks

typedef unsigned int u32;
typedef unsigned short u16;

__device__ __forceinline__ float logsigf(float x) {
  return fminf(x, 0.f) - log1pf(expf(-fabsf(x)));
}

// ---- bf16 helpers (storage bf16, math fp32) ----
__device__ __forceinline__ float lo16(u32 u) { return __uint_as_float(u << 16); }
__device__ __forceinline__ float hi16(u32 u) { return __uint_as_float(u & 0xFFFF0000u); }
__device__ __forceinline__ u32 pk2(float a, float b) {  // RNE pack
  u32 ua = __float_as_uint(a), ub = __float_as_uint(b);
  u32 ra = (ua + 0x7FFFu + ((ua >> 16) & 1u)) >> 16;
  u32 rb = (ub + 0x7FFFu + ((ub >> 16) & 1u)) >> 16;
  return (ra & 0xFFFFu) | (rb << 16);
}
__device__ __forceinline__ float bfat(const u16* __restrict__ p, size_t off) {
  return __uint_as_float(((u32)p[off]) << 16);
}
__device__ __forceinline__ void accum8(float* a, float w, uint4 x) {
  a[0] += w * lo16(x.x); a[1] += w * hi16(x.x);
  a[2] += w * lo16(x.y); a[3] += w * hi16(x.y);
  a[4] += w * lo16(x.z); a[5] += w * hi16(x.z);
  a[6] += w * lo16(x.w); a[7] += w * hi16(x.w);
}
__device__ __forceinline__ uint4 pack8(const float* a, float w) {
  return make_uint4(pk2(w * a[0], w * a[1]), pk2(w * a[2], w * a[3]),
                    pk2(w * a[4], w * a[5]), pk2(w * a[6], w * a[7]));
}

// ---- fp16 weight-pair pack/unpack ----
__device__ __forceinline__ u32 wpack(float a, float b) {
  __half2 h = __floats2half2_rn(a, b);
  return *reinterpret_cast<u32*>(&h);
}
__device__ __forceinline__ float2 hun(int wb) {
  __half2 h;
  *reinterpret_cast<int*>(&h) = wb;
  return __half22float2(h);
}

// ================= CSR build via bucket binning =================
// seg 0 = tgt, 1 = aux0, 2 = aux1. Directed entry packed: (dst_local<<18)|src.

// Fused: hist blocks (x < histB) + emb bf16 conversion blocks (independent).
__global__ void hist_cvt_kernel(const int2* __restrict__ tgt, const int2* __restrict__ aux,
                                int E, int Nu, int BPS, int histB, int* __restrict__ bcur,
                                const float4* __restrict__ ue, long nu2h,
                                const float4* __restrict__ ie, long ni2h,
                                u32* __restrict__ emb) {
  __shared__ int lh[NBK];
  int x = blockIdx.x;
  if (x >= histB) {
    long i2 = (long)(x - histB) * blockDim.x + threadIdx.x;
    if (i2 < nu2h + ni2h) {
      float4 v = (i2 < nu2h) ? ue[i2] : ie[i2 - nu2h];
      uint2 o = make_uint2(pk2(v.x, v.y), pk2(v.z, v.w));
      *reinterpret_cast<uint2*>(emb + 2 * i2) = o;
    }
    return;
  }
  int seg = x / BPS;
  int blk = x - seg * BPS;
  const int2* edges = (seg == 0) ? tgt : aux + (size_t)(seg - 1) * E;
  for (int b = threadIdx.x; b < NBK; b += 256) lh[b] = 0;
  __syncthreads();
  int e0 = blk * TILE_H;
  for (int k = threadIdx.x; k < TILE_H; k += 256) {
    int e = e0 + k;
    if (e < E) {
      int2 ed = edges[e];
      atomicAdd(&lh[ed.x >> BSHIFT], 1);
      atomicAdd(&lh[(ed.y + Nu) >> BSHIFT], 1);
    }
  }
  __syncthreads();
  for (int b = threadIdx.x; b < NBK; b += 256)
    if (lh[b]) atomicAdd(&bcur[seg * NBK + b], lh[b]);
}

// bscan + accs zeroing (folds away one hipMemsetAsync dispatch; accs is not
// read until de_score_sumsq, far downstream).
__global__ void bscan_kernel(int* __restrict__ bcur, float* __restrict__ accs, int nacc) {
  if (blockIdx.x == 0 && threadIdx.x < nacc) accs[threadIdx.x] = 0.f;
  int* b = bcur + blockIdx.x * NBK;
  int lane = threadIdx.x;
  int carry = 0;
  for (int base = 0; base < NBK; base += 64) {
    int i = base + lane;
    int v = b[i];
    int s = v;
    #pragma unroll
    for (int o = 1; o < 64; o <<= 1) {
      int t = __shfl_up(s, o);
      if (lane >= o) s += t;
    }
    b[i] = carry + s - v;
    carry += __shfl(s, 63);
  }
}

// 3-phase direct binning: LDS hist+rank -> global bucket reserve -> direct
// chunk-contiguous global stores.
__global__ void bin_kernel(const int2* __restrict__ tgt, const int2* __restrict__ aux,
                           int E, int Nu, int BPS, int* __restrict__ bcur,
                           int* __restrict__ binned) {
  __shared__ int lh[NBK];
  __shared__ int gb[NBK];
  int seg = blockIdx.x / BPS;
  int blk = blockIdx.x - seg * BPS;
  const int2* edges = (seg == 0) ? tgt : aux + (size_t)(seg - 1) * E;
  int* out = binned + (size_t)seg * 2 * E;
  int tid = threadIdx.x;
  for (int b = tid; b < NBK; b += 256) lh[b] = 0;
  __syncthreads();
  int e0 = blk * TILE_BIN;
  int pkv[16];
  int pb[16];
  int pr[16];
  #pragma unroll
  for (int it = 0; it < 8; ++it) {
    int e = e0 + tid + it * 256;
    bool ok = e < E;
    int2 ed = ok ? edges[e] : make_int2(0, -Nu);
    int u = ed.x, v = ed.y + Nu;
    int b1 = u >> BSHIFT, b2 = v >> BSHIFT;
    pkv[2 * it] = ((u & 255) << 18) | v;
    pb[2 * it] = b1;
    pr[2 * it] = ok ? atomicAdd(&lh[b1], 1) : 0;
    pkv[2 * it + 1] = ((v & 255) << 18) | u;
    pb[2 * it + 1] = b2;
    pr[2 * it + 1] = ok ? atomicAdd(&lh[b2], 1) : 0;
  }
  __syncthreads();
  #pragma unroll
  for (int j = 0; j < 4; ++j) {
    int b = tid * 4 + j;
    int c = lh[b];
    gb[b] = c ? atomicAdd(&bcur[seg * NBK + b], c) : 0;
  }
  __syncthreads();
  #pragma unroll
  for (int it = 0; it < 16; ++it) {
    int e = e0 + tid + (it >> 1) * 256;
    if (e < E) out[gb[pb[it]] + pr[it]] = pkv[it];
  }
}

// Count pass: per-node degree + row pointers (absolute within segment).
__global__ void csr_count_kernel(const int* __restrict__ binned,
                                 const int* __restrict__ bend, int E2, int N, int NBKe,
                                 int* __restrict__ deg3, int* __restrict__ rp3) {
  __shared__ int cnt[256];
  __shared__ int wred[4];
  int seg = blockIdx.x / NBKe;
  int bkt = blockIdx.x - seg * NBKe;
  int node0 = bkt << BSHIFT;
  const int* bc = bend + seg * NBK;
  int start = (bkt == 0) ? 0 : bc[bkt - 1];
  int end = bc[bkt];
  int cntE = end - start;
  const int* src = binned + (size_t)seg * E2 + start;
  cnt[threadIdx.x] = 0;
  __syncthreads();
  for (int k = threadIdx.x; k < cntE; k += 256) atomicAdd(&cnt[src[k] >> 18], 1);
  __syncthreads();
  int lane = threadIdx.x & 63, wid = threadIdx.x >> 6;
  int v = cnt[threadIdx.x];
  int incl = v;
  #pragma unroll
  for (int o = 1; o < 64; o <<= 1) {
    int t = __shfl_up(incl, o);
    if (lane >= o) incl += t;
  }
  if (lane == 63) wred[wid] = incl;
  __syncthreads();
  int wbase = 0;
  for (int w = 0; w < wid; ++w) wbase += wred[w];
  int node = node0 + (int)threadIdx.x;
  if (node < N) {
    deg3[(size_t)seg * N + node] = v;
    rp3[(size_t)seg * (N + 1) + node] = start + wbase + incl - v;
  }
  if (bkt == 0 && threadIdx.x == 0) rp3[(size_t)seg * (N + 1) + N] = E2;
}

// dinv + packed per-segment half2 weight tables (L2-resident, used by scatter).
__global__ void dinv_all_kernel(const int* __restrict__ deg3, float* __restrict__ dinv5,
                                u32* __restrict__ wtab, int N) {
  int n = blockIdx.x * blockDim.x + threadIdx.x;
  if (n >= N) return;
  int dt = deg3[n], d0 = deg3[N + n], d1 = deg3[2 * N + n];
  float wt  = dt ? rsqrtf((float)dt) : 0.f;
  float wa0 = d0 ? rsqrtf((float)d0) : 0.f;
  float wa1 = d1 ? rsqrtf((float)d1) : 0.f;
  int c0 = dt + d0, c1 = dt + d1;
  float wc0 = c0 ? rsqrtf((float)c0) : 0.f;
  float wc1 = c1 ? rsqrtf((float)c1) : 0.f;
  dinv5[n] = wt;
  dinv5[N + n] = wa0;
  dinv5[2 * N + n] = wa1;
  dinv5[3 * N + n] = wc0;
  dinv5[4 * N + n] = wc1;
  wtab[n] = wpack(wc0, wc1);
  wtab[N + n] = wpack(wa0, wc0);
  wtab[2 * N + n] = wpack(wa1, wc1);
}

// Scatter pass (after dinv): write packed 8B entries {col, half2 weights from wtab}.
__global__ void csr_scatter_kernel(const int* __restrict__ binned,
                                   const int* __restrict__ bend,
                                   const int* __restrict__ rp3,
                                   const u32* __restrict__ wtab,
                                   int E2, int N, int NBKe,
                                   int2* __restrict__ pk) {
  __shared__ int cnt[256];
  __shared__ int off[256];
  int seg = blockIdx.x / NBKe;
  int bkt = blockIdx.x - seg * NBKe;
  int node0 = bkt << BSHIFT;
  const int* bc = bend + seg * NBK;
  int start = (bkt == 0) ? 0 : bc[bkt - 1];
  int end = bc[bkt];
  int cntE = end - start;
  const int* src = binned + (size_t)seg * E2 + start;
  int node = node0 + (int)threadIdx.x;
  off[threadIdx.x] = (node < N) ? rp3[(size_t)seg * (N + 1) + node] : 0;
  cnt[threadIdx.x] = 0;
  const u32* wt = wtab + (size_t)seg * N;
  __syncthreads();
  int2* out = pk + (size_t)seg * E2;
  for (int k = threadIdx.x; k < cntE; k += 256) {
    int en = src[k];
    int lb = en >> 18;
    int c = en & 0x3FFFF;
    int pos = atomicAdd(&cnt[lb], 1);
    out[off[lb] + pos] = make_int2(c, (int)wt[c]);
  }
}

// ================= dense propagation (bf16 rows) =================

__device__ __forceinline__ void edge1_dual(const int2* __restrict__ p, int j, int lane,
                                           const uint4* __restrict__ rows,
                                           float* a1, float* a2) {
  int2 en = p[j];
  float2 w = hun(en.y);
  uint4 x = rows[(size_t)en.x * 4 + lane];
  accum8(a1, w.x, x);
  accum8(a2, w.y, x);
}

__device__ __forceinline__ void stream_dual(const int* __restrict__ rp,
                                            const int2* __restrict__ p, int n, int lane,
                                            const uint4* __restrict__ rows,
                                            float* a1, float* a2) {
  int j = rp[n], e = rp[n + 1];
  if ((j & 1) && j < e) { edge1_dual(p, j, lane, rows, a1, a2); ++j; }
  for (; j + 3 < e; j += 4) {
    int4 m0 = *reinterpret_cast<const int4*>(p + j);
    int4 m1 = *reinterpret_cast<const int4*>(p + j + 2);
    uint4 x0 = rows[(size_t)m0.x * 4 + lane];
    uint4 x1 = rows[(size_t)m0.z * 4 + lane];
    uint4 x2 = rows[(size_t)m1.x * 4 + lane];
    uint4 x3 = rows[(size_t)m1.z * 4 + lane];
    float2 w0 = hun(m0.y), w1 = hun(m0.w), w2 = hun(m1.y), w3 = hun(m1.w);
    accum8(a1, w0.x, x0); accum8(a2, w0.y, x0);
    accum8(a1, w1.x, x1); accum8(a2, w1.y, x1);
    accum8(a1, w2.x, x2); accum8(a2, w2.y, x2);
    accum8(a1, w3.x, x3); accum8(a2, w3.y, x3);
  }
  for (; j < e; ++j) edge1_dual(p, j, lane, rows, a1, a2);
}

// layer-1 for BOTH idx. tgt rows read ONCE. 4 lanes/node.
__global__ void gather_fused_all_kernel(const int* __restrict__ rp3,
                                        const int2* __restrict__ pk,
                                        const float* __restrict__ dinv5,
                                        const uint4* __restrict__ emb,
                                        uint4* __restrict__ BaAll, uint4* __restrict__ BcAll,
                                        int N, int E2) {
  const int* rpA0 = rp3 + (size_t)(N + 1);
  const int* rpA1 = rp3 + 2 * (size_t)(N + 1);
  const int2* pT = pk;
  const int2* pA0 = pk + (size_t)E2;
  const int2* pA1 = pk + 2 * (size_t)E2;
  const float* dvA0 = dinv5 + (size_t)N;
  const float* dvA1 = dinv5 + 2 * (size_t)N;
  const float* dvC0 = dinv5 + 3 * (size_t)N;
  const float* dvC1 = dinv5 + 4 * (size_t)N;
  int t = blockIdx.x * blockDim.x + threadIdx.x;
  int n = t >> 2;
  if (n >= N) return;
  int lane = t & 3;
  float aA0[8] = {0, 0, 0, 0, 0, 0, 0, 0};
  float aA1[8] = {0, 0, 0, 0, 0, 0, 0, 0};
  float aC0[8] = {0, 0, 0, 0, 0, 0, 0, 0};
  float aC1[8] = {0, 0, 0, 0, 0, 0, 0, 0};
  stream_dual(rpA0, pA0, n, lane, emb, aA0, aC0);   // seg1: (wA0, wC0)
  stream_dual(rpA1, pA1, n, lane, emb, aA1, aC1);   // seg2: (wA1, wC1)
  stream_dual(rp3, pT, n, lane, emb, aC0, aC1);     // seg0: (wC0, wC1)
  size_t o = (size_t)n * 4 + lane;
  size_t rowN4 = (size_t)N * 4;
  BaAll[o] = pack8(aA0, dvA0[n]);
  BaAll[rowN4 + o] = pack8(aA1, dvA1[n]);
  BcAll[o] = pack8(aC0, dvC0[n]);
  BcAll[rowN4 + o] = pack8(aC1, dvC1[n]);
}

// ---- fused gather_avg + ce_sparse bodies (independent; co-scheduled) ----

__device__ __forceinline__ void gather_avg_body(int bx, int idx,
                                  const int* __restrict__ rp3, const int2* __restrict__ pk,
                                  const float* __restrict__ dinv5,
                                  const uint4* __restrict__ emb,
                                  const uint4* __restrict__ BaAll, uint4* __restrict__ AI,
                                  int N, int E2) {
  const int* rp = rp3 + (size_t)(1 + idx) * (N + 1);
  const int2* pA = pk + (size_t)(1 + idx) * E2;
  const float* dv = dinv5 + (size_t)(1 + idx) * N;
  const uint4* cur = BaAll + (size_t)idx * N * 4;
  int t = bx * 256 + threadIdx.x;
  int n = t >> 2;
  if (n >= N) return;
  int lane = t & 3;
  float acc[8] = {0, 0, 0, 0, 0, 0, 0, 0};
  int j = rp[n], e = rp[n + 1];
  if ((j & 1) && j < e) {
    int2 en = pA[j];
    uint4 x = cur[(size_t)en.x * 4 + lane];
    accum8(acc, hun(en.y).x, x);
    ++j;
  }
  for (; j + 3 < e; j += 4) {
    int4 m0 = *reinterpret_cast<const int4*>(pA + j);
    int4 m1 = *reinterpret_cast<const int4*>(pA + j + 2);
    uint4 x0 = cur[(size_t)m0.x * 4 + lane];
    uint4 x1 = cur[(size_t)m0.z * 4 + lane];
    uint4 x2 = cur[(size_t)m1.x * 4 + lane];
    uint4 x3 = cur[(size_t)m1.z * 4 + lane];
    accum8(acc, hun(m0.y).x, x0);
    accum8(acc, hun(m0.w).x, x1);
    accum8(acc, hun(m1.y).x, x2);
    accum8(acc, hun(m1.w).x, x3);
  }
  for (; j < e; ++j) {
    int2 en = pA[j];
    uint4 x = cur[(size_t)en.x * 4 + lane];
    accum8(acc, hun(en.y).x, x);
  }
  float wn = dv[n];
  uint4 e4 = emb[(size_t)n * 4 + lane];
  uint4 b4 = cur[(size_t)n * 4 + lane];
  float r[8];
  r[0] = (lo16(e4.x) + lo16(b4.x) + wn * acc[0]) * (1.f / 3.f);
  r[1] = (hi16(e4.x) + hi16(b4.x) + wn * acc[1]) * (1.f / 3.f);
  r[2] = (lo16(e4.y) + lo16(b4.y) + wn * acc[2]) * (1.f / 3.f);
  r[3] = (hi16(e4.y) + hi16(b4.y) + wn * acc[3]) * (1.f / 3.f);
  r[4] = (lo16(e4.z) + lo16(b4.z) + wn * acc[4]) * (1.f / 3.f);
  r[5] = (hi16(e4.z) + hi16(b4.z) + wn * acc[5]) * (1.f / 3.f);
  r[6] = (lo16(e4.w) + lo16(b4.w) + wn * acc[6]) * (1.f / 3.f);
  r[7] = (hi16(e4.w) + hi16(b4.w) + wn * acc[7]) * (1.f / 3.f);
  AI[(size_t)n * 8 + idx * 4 + lane] = pack8(r, 1.f);
}

__device__ __forceinline__ float fdim2(const int2* __restrict__ pkA, const int2* __restrict__ pkT,
                                       const int* __restrict__ rpA, const int* __restrict__ rpT,
                                       int idx, const float* __restrict__ dv,
                                       const u16* __restrict__ base, const u16* __restrict__ L1,
                                       int r, int d) {
  float acc = 0.f;
  for (int j = rpA[r]; j < rpA[r + 1]; ++j) {
    int2 en = pkA[j];
    acc += hun(en.y).y * bfat(L1, (size_t)en.x * D + d);
  }
  for (int j = rpT[r]; j < rpT[r + 1]; ++j) {
    int2 en = pkT[j];
    float2 w = hun(en.y);
    acc += (idx ? w.y : w.x) * bfat(L1, (size_t)en.x * D + d);
  }
  return (bfat(base, (size_t)r * D + d) + bfat(L1, (size_t)r * D + d) + dv[r] * acc) * (1.f / 3.f);
}

__device__ __forceinline__ void ce_body(int bx, int idx,
                                 const int* __restrict__ rp3, const int2* __restrict__ pk,
                                 const float* __restrict__ dinv5,
                                 const u32* __restrict__ EMBu, const u32* __restrict__ BcAll,
                                 const int* __restrict__ batch, int Bsz, int Nu, int N, int E2,
                                 float* __restrict__ cps, float* __restrict__ cns) {
  const int* rpA = rp3 + (size_t)(1 + idx) * (N + 1);
  const int2* pkA = pk + (size_t)(1 + idx) * E2;
  const float* dv = dinv5 + (size_t)(3 + idx) * N;
  const u16* base = (const u16*)EMBu;
  const u16* L1 = (const u16*)(BcAll + (size_t)idx * N * ROWU);
  float* outp = cps + (size_t)idx * Bsz;
  float* outn = cns + (size_t)idx * Bsz;
  int t = bx * 256 + threadIdx.x;
  int b = t >> 5, d = t & 31;
  if (b >= Bsz) return;
  int u = batch[b * 9 + 0];
  int p = batch[b * 9 + 1] + Nu;
  int n = batch[b * 9 + 2] + Nu;
  float uv = fdim2(pkA, pk, rpA, rp3, idx, dv, base, L1, u, d);
  float pv = fdim2(pkA, pk, rpA, rp3, idx, dv, base, L1, p, d);
  float nv = fdim2(pkA, pk, rpA, rp3, idx, dv, base, L1, n, d);
  float sp = uv * pv, sn = uv * nv;
  #pragma unroll
  for (int o = 16; o > 0; o >>= 1) {
    sp += __shfl_down(sp, o, 32);
    sn += __shfl_down(sn, o, 32);
  }
  if (d == 0) {
    outp[b] = fmaxf(sp, 0.f);
    outn[b] = fmaxf(sn, 0.f);
  }
}

// LPT co-schedule: ce blocks (heavy, ~8x per-thread work) are issued within
// the FIRST 2*CEB blocks (mod-2 interleave) so they start at t=0 and the
// lighter avg sea fills in behind them -- removes the late pure-ce tail.
__global__ void gather_avg_ce_kernel(const int* __restrict__ rp3, const int2* __restrict__ pk,
                                     const float* __restrict__ dinv5,
                                     const uint4* __restrict__ emb,
                                     const uint4* __restrict__ BaAll, uint4* __restrict__ AI,
                                     const u32* __restrict__ EMBu, const u32* __restrict__ BcAll,
                                     const int* __restrict__ batch, int Bsz, int Nu,
                                     int N, int E2, int CEB,
                                     float* __restrict__ cps, float* __restrict__ cns) {
  int x = blockIdx.x;
  int idx = blockIdx.y;
  int lim = 2 * CEB;
  if (x < lim && (x & 1)) {
    ce_body(x >> 1, idx, rp3, pk, dinv5, EMBu, BcAll, batch, Bsz, Nu, N, E2, cps, cns);
  } else {
    int ceBefore = (x < lim) ? ((x + 1) >> 1) : CEB;
    gather_avg_body(x - ceBefore, idx, rp3, pk, dinv5, emb, BaAll, AI, N, E2);
  }
}

// ---- fused de_gather + score_aux + sumsq2 (independent; score/sumsq first) ----

__device__ __forceinline__ float dotrow(const u32* __restrict__ a, const u32* __restrict__ b) {
  float s = 0.f;
  #pragma unroll
  for (int k = 0; k < ROWU; ++k) {
    u32 x = a[k], y = b[k];
    s += lo16(x) * lo16(y) + hi16(x) * hi16(y);
  }
  return s;
}

__global__ void de_score_sumsq_kernel(const int* __restrict__ rp3, const int2* __restrict__ pk,
                                      const float* __restrict__ dinv5,
                                      const uint4* __restrict__ AI4, uint4* __restrict__ DeI,
                                      const u32* __restrict__ AI, const int* __restrict__ batch,
                                      int Bsz, int Nu, int N, int NA, int gBs,
                                      float* __restrict__ aps, float* __restrict__ ans_,
                                      float* __restrict__ accs,
                                      const float4* __restrict__ xu, int n4u,
                                      const float4* __restrict__ xi, int n4i) {
  __shared__ float redU[4], redI[4];
  int x = blockIdx.x;
  int scoreB = gBs * NA;
  int tid = threadIdx.x;
  if (x < scoreB) {
    // ---- score_aux ----
    int idx = x / gBs;
    int bx = x - idx * gBs;
    const u32* A = AI + (size_t)idx * ROWU;
    float* outp = aps + (size_t)idx * Bsz;
    float* outn = ans_ + (size_t)idx * Bsz;
    int b = bx * 256 + tid;
    float l = 0.f;
    if (b < Bsz) {
      int u = batch[b * 9 + 0];
      int p = batch[b * 9 + 1] + Nu;
      int n = batch[b * 9 + 2] + Nu;
      const u32* ur = A + (size_t)u * 32;
      outp[b] = fmaxf(dotrow(ur, A + (size_t)p * 32), 0.f);
      outn[b] = fmaxf(dotrow(ur, A + (size_t)n * 32), 0.f);
      const int* r = batch + b * 9 + 3 * (1 + idx);
      const u32* aur = A + (size_t)r[0] * 32;
      float ps = dotrow(aur, A + (size_t)(r[1] + Nu) * 32);
      float ns = dotrow(aur, A + (size_t)(r[2] + Nu) * 32);
      l = -logsigf(ps - ns);
    }
    for (int o = 32; o > 0; o >>= 1) l += __shfl_down(l, o);
    if ((tid & 63) == 0) atomicAdd(&accs[idx], l);
    return;
  }
  if (x < scoreB + SQB) {
    // ---- sumsq2 ----
    int bx = x - scoreB;
    int gid = bx * 256 + tid;
    int stride = SQB * 256;
    float su = 0.f, si = 0.f;
    for (int i = gid; i < n4u; i += stride) {
      float4 v = xu[i];
      su += v.x * v.x + v.y * v.y + v.z * v.z + v.w * v.w;
    }
    for (int i = gid; i < n4i; i += stride) {
      float4 v = xi[i];
      si += v.x * v.x + v.y * v.y + v.z * v.z + v.w * v.w;
    }
    for (int o = 32; o > 0; o >>= 1) {
      su += __shfl_down(su, o);
      si += __shfl_down(si, o);
    }
    if ((tid & 63) == 0) { redU[tid >> 6] = su; redI[tid >> 6] = si; }
    __syncthreads();
    if (tid == 0) {
      atomicAdd(&accs[NA + 1], redU[0] + redU[1] + redU[2] + redU[3]);
      atomicAdd(&accs[NA + 2], redI[0] + redI[1] + redI[2] + redI[3]);
    }
    return;
  }
  // ---- de_gather ----
  int bx = x - scoreB - SQB;
  int t = bx * 256 + tid;
  int n = t >> 3;
  if (n >= N) return;
  int lane = t & 7;
  float acc[8] = {0, 0, 0, 0, 0, 0, 0, 0};
  int j = rp3[n], e = rp3[n + 1];
  if ((j & 1) && j < e) {
    int c = pk[j].x;
    uint4 xr = AI4[(size_t)c * 8 + lane];
    accum8(acc, dinv5[c], xr);
    ++j;
  }
  for (; j + 3 < e; j += 4) {
    int4 m0 = *reinterpret_cast<const int4*>(pk + j);
    int4 m1 = *reinterpret_cast<const int4*>(pk + j + 2);
    uint4 x0 = AI4[(size_t)m0.x * 8 + lane];
    uint4 x1 = AI4[(size_t)m0.z * 8 + lane];
    uint4 x2 = AI4[(size_t)m1.x * 8 + lane];
    uint4 x3 = AI4[(size_t)m1.z * 8 + lane];
    accum8(acc, dinv5[m0.x], x0);
    accum8(acc, dinv5[m0.z], x1);
    accum8(acc, dinv5[m1.x], x2);
    accum8(acc, dinv5[m1.z], x3);
  }
  for (; j < e; ++j) {
    int c = pk[j].x;
    uint4 xr = AI4[(size_t)c * 8 + lane];
    accum8(acc, dinv5[c], xr);
  }
  DeI[(size_t)n * 8 + lane] = pack8(acc, dinv5[n]);
}

// ================= de sparse + recloss fused =================
// 64 lanes per batch item: idx = lane>>5, d = lane&31. Both idx halves share
// each 128 B interleaved AI/DeI row and the tgt edge walk; BPR rec-loss
// finished in-register via cross-half shuffles.

__device__ __forceinline__ float fdim1i(const int2* __restrict__ pkT, const int* __restrict__ rp,
                                        const float* __restrict__ dv,
                                        const u16* __restrict__ base, const u16* __restrict__ L1,
                                        int r, int di) {
  float acc = 0.f;
  for (int j = rp[r]; j < rp[r + 1]; ++j) {
    int2 en = pkT[j];
    acc += dv[en.x] * bfat(L1, (size_t)en.x * 64 + di);
  }
  return (bfat(base, (size_t)r * 64 + di) + bfat(L1, (size_t)r * 64 + di) + dv[r] * acc) * (1.f / 3.f);
}

__global__ void de_sparse_rec_kernel(const int* __restrict__ rp3, const int2* __restrict__ pk,
                                     const float* __restrict__ dinv5,
                                     const u32* __restrict__ AI, const u32* __restrict__ DeI,
                                     const int* __restrict__ batch,
                                     const float* __restrict__ cps, const float* __restrict__ cns,
                                     const float* __restrict__ aps, const float* __restrict__ ans_,
                                     int Bsz, int Nu, int N, int NA, float* __restrict__ acc) {
  __shared__ float red[4];
  int tid = threadIdx.x;
  int t = blockIdx.x * 256 + tid;
  int b = t >> 6;
  int lane = tid & 63;
  int d = lane & 31;
  int idx = lane >> 5;
  float l = 0.f;
  if (b < Bsz) {
    const u16* base = (const u16*)AI;
    const u16* L1 = (const u16*)DeI;
    int di = idx * 32 + d;
    int u = batch[b * 9 + 0];
    int p = batch[b * 9 + 1] + Nu;
    int n = batch[b * 9 + 2] + Nu;
    float uv = fdim1i(pk, rp3, dinv5, base, L1, u, di);
    float pv = fdim1i(pk, rp3, dinv5, base, L1, p, di);
    float nv = fdim1i(pk, rp3, dinv5, base, L1, n, di);
    float sp = uv * pv, sn = uv * nv;
    #pragma unroll
    for (int o = 16; o > 0; o >>= 1) {
      sp += __shfl_xor(sp, o, 32);
      sn += __shfl_xor(sn, o, 32);
    }
    sp = fmaxf(sp, 0.f);           // per-idx relu'd de score, in all 32 lanes of half
    sn = fmaxf(sn, 0.f);
    float dp = sp + __shfl_xor(sp, 32);   // sum over idx (width 64)
    float dn = sn + __shfl_xor(sn, 32);
    if (lane == 0) {
      float cap = 0.f, can = 0.f;
      for (int i = 0; i < NA; ++i) {
        cap += cps[(size_t)i * Bsz + b] * aps[(size_t)i * Bsz + b];
        can += cns[(size_t)i * Bsz + b] * ans_[(size_t)i * Bsz + b];
      }
      l = -logsigf(dp * cap - dn * can);
    }
  }
  if ((tid & 63) == 0) red[tid >> 6] = l;
  __syncthreads();
  if (tid == 0) atomicAdd(acc, red[0] + red[1] + red[2] + red[3]);
}

__global__ void final_kernel(const float* __restrict__ accs, int Bsz, int NA, int NiRows,
                             float* __restrict__ out) {
  float rec = accs[NA] / (float)Bsz;
  float aux = 0.f;
  for (int i = 0; i < NA; ++i) aux += accs[i] / (float)Bsz;
  aux /= (float)NA;
  float embl = (sqrtf(accs[NA + 1]) + sqrtf(accs[NA + 2])) / (float)NiRows;
  out[0] = rec + 0.5f * aux + 1e-4f * embl;
}

extern "C" void kernel_launch(void* const* d_in, const int* in_sizes, int n_in,
                              void* d_out, int out_size, void* d_ws, size_t ws_size,
                              hipStream_t stream) {
  const float* user_emb = (const float*)d_in[0];
  const float* item_emb = (const float*)d_in[1];
  const int* batch = (const int*)d_in[2];
  const int* aux_edges = (const int*)d_in[3];
  const int* tgt_edges = (const int*)d_in[4];

  const int NuRows = in_sizes[0] / D;          // 100001
  const int NiRows = in_sizes[1] / D;          // 50001
  const int Bsz = in_sizes[2] / 9;             // 4096
  const int E = in_sizes[4] / 2;               // 1,000,000
  const int NA = in_sizes[3] / (2 * E);        // 2
  const int N = NuRows + NiRows;               // 150002 < 2^18 (pack invariant)
  const int E2 = 2 * E;
  const size_t rowH = (size_t)N * ROWU;
  const int BPS_H = (E + TILE_H - 1) / TILE_H;
  const int BPS_B = (E + TILE_BIN - 1) / TILE_BIN;
  const int NBKe = (N + (1 << BSHIFT) - 1) >> BSHIFT;

  // ---- workspace layout ----
  u32* EMBu = (u32*)d_ws;                 // rowH (planar)
  u32* AI = EMBu + rowH;                  // 2*rowH (INTERLEAVED per node)
  u32* BaAll = AI + 2 * rowH;             // 2*rowH (planar aux L1; later interleaved De)
  u32* BcAll = BaAll + 2 * rowH;          // 2*rowH (planar comb L1)
  int* deg3 = (int*)(BcAll + 2 * rowH);           // 3*N
  float* dinv5 = (float*)(deg3 + 3 * (size_t)N);  // 5*N
  u32* wtab = (u32*)(dinv5 + 5 * (size_t)N);      // 3*N packed half2 weight tables
  int* rp3 = (int*)(wtab + 3 * (size_t)N);        // 3*(N+1)
  int* bcur = rp3 + 3 * (size_t)(N + 1);          // 3*NBK
  uintptr_t pka = ((uintptr_t)(bcur + 3 * (size_t)NBK) + 15) & ~(uintptr_t)15;
  int2* pk = (int2*)pka;                          // 3*E2 packed entries (8 B each), 16B-aligned
  float* cps = (float*)(pk + 3 * (size_t)E2);
  float* cns = cps + (size_t)NA * Bsz;
  float* aps = cns + (size_t)NA * Bsz;
  float* ans_ = aps + (size_t)NA * Bsz;
  float* accs = ans_ + (size_t)NA * Bsz;          // [NA aux][rec][sumsq_u][sumsq_i]
  int* binned = (int*)AI;  // 24 MB alias spanning AI+BaAll; dead before gathers

  const int TB = 256;
  const int gN = (N + TB - 1) / TB;
  const int gN4 = (N * 4 + TB - 1) / TB;
  const int gN8 = (N * 8 + TB - 1) / TB;
  const int gB = (Bsz + TB - 1) / TB;
  const int gB32 = (Bsz * 32 + TB - 1) / TB;
  const int gB64 = (Bsz * 64 + TB - 1) / TB;
  const long nu2 = (long)NuRows * ROWU;
  const long ni2 = (long)NiRows * ROWU;
  const long nu2h = nu2 / 2, ni2h = ni2 / 2;
  const int gCvt2 = (int)((nu2h + ni2h + TB - 1) / TB);
  const int histB = 3 * BPS_H;

  // ---- binned CSR build (+ emb conversion co-scheduled) ----
  hipMemsetAsync(bcur, 0, 3 * (size_t)NBK * sizeof(int), stream);
  hist_cvt_kernel<<<histB + gCvt2, TB, 0, stream>>>(
      (const int2*)tgt_edges, (const int2*)aux_edges, E, NuRows, BPS_H, histB, bcur,
      (const float4*)user_emb, nu2h, (const float4*)item_emb, ni2h, EMBu);
  bscan_kernel<<<3, 64, 0, stream>>>(bcur, accs, NA + 3);
  bin_kernel<<<3 * BPS_B, TB, 0, stream>>>((const int2*)tgt_edges, (const int2*)aux_edges,
                                           E, NuRows, BPS_B, bcur, binned);
  csr_count_kernel<<<3 * NBKe, TB, 0, stream>>>(binned, bcur, E2, N, NBKe, deg3, rp3);
  dinv_all_kernel<<<gN, TB, 0, stream>>>(deg3, dinv5, wtab, N);
  csr_scatter_kernel<<<3 * NBKe, TB, 0, stream>>>(binned, bcur, rp3, wtab, E2, N, NBKe, pk);

  gather_fused_all_kernel<<<gN4, TB, 0, stream>>>(rp3, pk, dinv5, (const uint4*)EMBu,
                                                  (uint4*)BaAll, (uint4*)BcAll, N, E2);

  dim3 gridAC(gN4 + gB32, NA);
  gather_avg_ce_kernel<<<gridAC, TB, 0, stream>>>(rp3, pk, dinv5, (const uint4*)EMBu,
                                                  (const uint4*)BaAll, (uint4*)AI,
                                                  EMBu, BcAll, batch, Bsz, NuRows,
                                                  N, E2, gB32, cps, cns);

  de_score_sumsq_kernel<<<gB * NA + SQB + gN8, TB, 0, stream>>>(
      rp3, pk, dinv5, (const uint4*)AI, (uint4*)BaAll, AI, batch,
      Bsz, NuRows, N, NA, gB, aps, ans_, accs,
      (const float4*)user_emb, (int)((size_t)NuRows * D / 4),
      (const float4*)item_emb, (int)((size_t)NiRows * D / 4));

  de_sparse_rec_kernel<<<gB64, TB, 0, stream>>>(rp3, pk, dinv5, AI, (const u32*)BaAll,
                                                batch, cps, cns, aps, ans_,
                                                Bsz, NuRows, N, NA, accs + NA);

  final_kernel<<<1, 1, 0, stream>>>(accs, Bsz, NA, NiRows, (float*)d_out);
}